// Round 2
// baseline (489.670 us; speedup 1.0000x reference)
//
#include <hip/hip_runtime.h>
#include <math.h>

#define DIMK 2048
#define NEMB 16384
#define NB 256
#define NR2 1536          // 256*6 neighbor rows
#define INV_BETA 20.0f
#define NEG_INF (-3.0e38f)

typedef short short8 __attribute__((ext_vector_type(8)));
typedef float f32x4 __attribute__((ext_vector_type(4)));
typedef const __attribute__((address_space(1))) unsigned int* gas_ptr;
typedef __attribute__((address_space(3))) unsigned int* las_ptr;

__device__ __forceinline__ void gl_lds16(const void* g, void* l) {
  __builtin_amdgcn_global_load_lds((gas_ptr)g, (las_ptr)l, 16, 0, 0);
}

__device__ __forceinline__ unsigned short f2bf(float f) {
  unsigned u = __float_as_uint(f);
  u += 0x7fffu + ((u >> 16) & 1u);
  return (unsigned short)(u >> 16);
}

// top-6 insert with (value desc, index asc) tie-break — matches jax top_k order
__device__ __forceinline__ void ins6i(float x, int xi, float v[6], int vi[6]) {
  if (x > v[5] || (x == v[5] && xi < vi[5])) {
    v[5] = x; vi[5] = xi;
#pragma unroll
    for (int j = 5; j > 0; j--) {
      if (v[j] > v[j - 1] || (v[j] == v[j - 1] && vi[j] < vi[j - 1])) {
        float tv = v[j]; v[j] = v[j - 1]; v[j - 1] = tv;
        int ti = vi[j]; vi[j] = vi[j - 1]; vi[j - 1] = ti;
      }
    }
  }
}

__global__ __launch_bounds__(256) void cvt_kernel(const float* __restrict__ src,
                                                  unsigned short* __restrict__ dst, int n4) {
  int i = blockIdx.x * 256 + threadIdx.x;
  if (i < n4) {
    float4 f = ((const float4*)src)[i];
    ushort4 o;
    o.x = f2bf(f.x); o.y = f2bf(f.y); o.z = f2bf(f.z); o.w = f2bf(f.w);
    ((ushort4*)dst)[i] = o;
  }
}

// Staging: NSUB subtiles of [16 rows x 32 k] bf16 (1 KB each) PER K-HALF (BK=64 ->
// two halves, 2*NSUB KB total). Fragment-contiguous: chunk for (row=lane&15,
// kseg=lane>>4) at byte offset lane*16 -> conflict-free b128.
//
// MODE 0: C = X(256xK) * em^T -> logits*20 (fp32 out). tile 64(M)x128(N), grid (128,4)
// MODE 1: C = em[nidx](1536xK) * em^T. NO value output: epilogue directly counts
//         acc > sa[row] per row (exact-count formulation of the recip test) and
//         atomically accumulates into cntOut[1536].
template <int MODE>
__global__ __launch_bounds__(256, 4) void gemm_kernel(
    const unsigned short* __restrict__ Abase, const unsigned short* __restrict__ Bbase,
    const int* __restrict__ nidx, float* __restrict__ outC,
    const float* __restrict__ saIn, int* __restrict__ cntOut) {
  constexpr int MTILE = (MODE == 0) ? 64 : 128;
  constexpr int MI = 4;
  constexpr int NI = (MODE == 0) ? 2 : 4;
  constexpr int NSUB_A = MTILE / 16;   // 4 or 8
  constexpr int NSUB = NSUB_A + 8;     // 12 or 16
  constexpr int NA = NSUB / 4;         // 3 or 4 staging DMAs per wave per k-half

  __shared__ unsigned short st[2 * NSUB * 512];   // 24 KB (MODE0) / 32 KB (MODE1)
  __shared__ int rowIdxSh[128];
  __shared__ float saSh[128];
  __shared__ int cntSh[128];
  int t = threadIdx.x;
  int lane = t & 63, wave = t >> 6;
  int quad = lane >> 4, l16 = lane & 15;
  int wr = (MODE == 0) ? 0 : (wave >> 1);
  int wc = (MODE == 0) ? wave : (wave & 1);
  int bn = blockIdx.x, bm = blockIdx.y;

  if constexpr (MODE == 1) {
    if (t < 128) {
      rowIdxSh[t] = nidx[bm * 128 + t];
      saSh[t] = saIn[bm * 128 + t];
      cntSh[t] = 0;
    }
  }
  __syncthreads();

  const unsigned short* agp[NA];
  unsigned short* ldst[NA];
  {
    int seg = lane >> 4;
#pragma unroll
    for (int a = 0; a < NA; a++) {
      int s = wave + a * 4;
      const unsigned short* basep;
      size_t goff;
      if (s < NSUB_A) {
        int r = s * 16 + l16;
        int grow = (MODE == 0) ? (bm * MTILE + r) : rowIdxSh[r];
        basep = Abase;
        goff = (size_t)grow * DIMK;
      } else {
        int r = (s - NSUB_A) * 16 + l16;
        basep = Bbase;
        goff = (size_t)(bn * 128 + r) * DIMK;
      }
      agp[a] = basep + goff + seg * 8;
      ldst[a] = &st[s * 512];      // wave-uniform LDS base (k-half 0)
    }
  }

  f32x4 acc[MI][NI];
#pragma unroll
  for (int mi = 0; mi < MI; mi++)
#pragma unroll
    for (int ni = 0; ni < NI; ni++) acc[mi][ni] = (f32x4)0.0f;

  int lo = lane * 8;  // shorts: lane*16 bytes
  for (int k0 = 0; k0 < DIMK; k0 += 64) {
    __syncthreads();   // previous iter's fragment reads complete
#pragma unroll
    for (int a = 0; a < NA; a++) {
      gl_lds16(agp[a] + k0, ldst[a]);                             // k-half 0
      gl_lds16(agp[a] + k0 + 32, ldst[a] + NSUB * 512);           // k-half 1
    }
    __syncthreads();   // drains vmcnt -> staged data visible
#pragma unroll
    for (int h = 0; h < 2; h++) {
      const unsigned short* hb = &st[h * NSUB * 512];
      short8 af[MI], bfv[NI];
#pragma unroll
      for (int mi = 0; mi < MI; mi++)
        af[mi] = *(const short8*)&hb[(wr * MI + mi) * 512 + lo];
#pragma unroll
      for (int ni = 0; ni < NI; ni++)
        bfv[ni] = *(const short8*)&hb[(NSUB_A + wc * NI + ni) * 512 + lo];
#pragma unroll
      for (int mi = 0; mi < MI; mi++)
#pragma unroll
        for (int ni = 0; ni < NI; ni++)
          acc[mi][ni] =
              __builtin_amdgcn_mfma_f32_16x16x32_bf16(af[mi], bfv[ni], acc[mi][ni], 0, 0, 0);
    }
  }

  if constexpr (MODE == 0) {
#pragma unroll
    for (int mi = 0; mi < MI; mi++) {
      int row = bm * MTILE + mi * 16 + quad * 4;
#pragma unroll
      for (int ni = 0; ni < NI; ni++) {
        int col = bn * 128 + wave * 32 + ni * 16 + l16;
#pragma unroll
        for (int rr = 0; rr < 4; rr++)
          outC[(size_t)(row + rr) * NEMB + col] = acc[mi][ni][rr] * INV_BETA;
      }
    }
  } else {
    // count epilogue: lane holds rows (wr*64+mi*16+quad*4+rr), cols (wc*64+ni*16+l16)
#pragma unroll
    for (int mi = 0; mi < MI; mi++) {
#pragma unroll
      for (int rr = 0; rr < 4; rr++) {
        int rloc = wr * 64 + mi * 16 + quad * 4 + rr;
        float s = saSh[rloc];
        int c = 0;
#pragma unroll
        for (int ni = 0; ni < NI; ni++) c += (acc[mi][ni][rr] > s) ? 1 : 0;
        // reduce over the 16 lanes (l16) sharing this row; stays within quad group
        c += __shfl_xor(c, 1, 64);
        c += __shfl_xor(c, 2, 64);
        c += __shfl_xor(c, 4, 64);
        c += __shfl_xor(c, 8, 64);
        if (l16 == 0) atomicAdd(&cntSh[rloc], c);   // 2 waves (wc) x 4 quads per row
      }
    }
    __syncthreads();
    if (t < 128) atomicAdd(&cntOut[bm * 128 + t], cntSh[t]);
  }
}

// single-pass: per-thread top6(v,i) + two-pass in-register (max, then 16 INDEPENDENT
// exps that pipeline at v_exp throughput), then LDS tree merge.
// 1024 threads/block (16 elems/thread via 4x float4) -> 4 waves/SIMD.
__global__ __launch_bounds__(1024) void rowstats_kernel(
    const float* __restrict__ logits, float* __restrict__ topv,
    int* __restrict__ topi, float* __restrict__ lse) {
  int m = blockIdx.x, t = threadIdx.x;
  const float4* row4 = (const float4*)(logits + (size_t)m * NEMB);
  float v6[6]; int i6[6];
#pragma unroll
  for (int j = 0; j < 6; j++) { v6[j] = NEG_INF; i6[j] = 0x7fffffff; }
  float vals[16];
#pragma unroll
  for (int j = 0; j < 4; j++) {
    float4 f = row4[t + j * 1024];
    vals[j * 4 + 0] = f.x; vals[j * 4 + 1] = f.y;
    vals[j * 4 + 2] = f.z; vals[j * 4 + 3] = f.w;
  }
  float mx = vals[0];
#pragma unroll
  for (int r = 1; r < 16; r++) mx = fmaxf(mx, vals[r]);
  float sme = 0.f;
#pragma unroll
  for (int r = 0; r < 16; r++) sme += expf(vals[r] - mx);   // independent exps
#pragma unroll
  for (int j = 0; j < 4; j++) {
    int base = (t + j * 1024) * 4;
#pragma unroll
    for (int b = 0; b < 4; b++) ins6i(vals[j * 4 + b], base + b, v6, i6);
  }
  __shared__ float sv[1024 * 6]; __shared__ int si[1024 * 6];
  __shared__ float smx[1024], ssm[1024];
#pragma unroll
  for (int j = 0; j < 6; j++) { sv[t * 6 + j] = v6[j]; si[t * 6 + j] = i6[j]; }
  smx[t] = mx; ssm[t] = sme;
  __syncthreads();
  for (int s = 512; s > 0; s >>= 1) {
    if (t < s) {
      float mo = smx[t + s], lo = ssm[t + s];
      float mn = fmaxf(smx[t], mo);
      ssm[t] = ssm[t] * expf(smx[t] - mn) + lo * expf(mo - mn);
      smx[t] = mn;
#pragma unroll
      for (int j = 0; j < 6; j++) ins6i(sv[(t + s) * 6 + j], si[(t + s) * 6 + j], v6, i6);
#pragma unroll
      for (int j = 0; j < 6; j++) { sv[t * 6 + j] = v6[j]; si[t * 6 + j] = i6[j]; }
    }
    __syncthreads();
  }
  if (t == 0) {
    lse[m] = smx[0] + logf(ssm[0]);
#pragma unroll
    for (int j = 0; j < 6; j++) { topv[m * 6 + j] = v6[j]; topi[m * 6 + j] = i6[j]; }
  }
}

// exact fp32 dot: sa[r] = em[topi[r]] . em[anchor(m=r/6)]; also zeroes cnt[r]
__global__ __launch_bounds__(256) void sa_kernel(const float* __restrict__ em,
                                                 const int* __restrict__ topi,
                                                 float* __restrict__ sa,
                                                 int* __restrict__ cnt) {
  int gid = blockIdx.x * 256 + threadIdx.x;
  int w = gid >> 6, lane = gid & 63;
  if (w >= NR2) return;
  if (lane == 1) cnt[w] = 0;
  int m = w / 6;
  int i = topi[w], a = topi[m * 6];
  const float* ei = em + (size_t)i * DIMK;
  const float* ea = em + (size_t)a * DIMK;
  float s = 0.f;
  for (int d = lane; d < DIMK; d += 64) s += ei[d] * ea[d];
#pragma unroll
  for (int off = 32; off > 0; off >>= 1) s += __shfl_down(s, off, 64);
  if (lane == 0) sa[w] = s;
}

// recip[r] == (count of sims values strictly greater than sa[r]) < 6, computed inline
__global__ __launch_bounds__(256) void final_kernel(
    const float* __restrict__ logits, const float* __restrict__ topv,
    const int* __restrict__ topi, const float* __restrict__ lse_arr,
    const int* __restrict__ cnt, const int* __restrict__ targets,
    float* __restrict__ out) {
  int m = threadIdx.x;
  float lse = lse_arr[m];
  int tgt = targets[m];
  float tl = logits[(size_t)m * NEMB + tgt];
  float beta = 0.f, Ps = 0.f, nbp = 0.f;
  bool tin = false;
#pragma unroll
  for (int k = 0; k < 6; k++) {
    int idx = topi[m * 6 + k]; float v = topv[m * 6 + k];
    float p = expf(v - lse);
    if (idx == tgt) { tin = true; beta += (lse - v); Ps += p; }
    else if (cnt[m * 6 + k] < 6) { beta += 0.5f * (lse - v); Ps += p; nbp += p; }
  }
  if (!tin) { beta += (lse - tl); Ps += expf(tl - lse); }
  float alpha = 9.2103404f * (1.f - Ps) + 0.6931472f * nbp;
  __shared__ float sA[256], sB2[256];
  sA[m] = alpha; sB2[m] = beta;
  __syncthreads();
  for (int s = 128; s > 0; s >>= 1) {
    if (m < s) { sA[m] += sA[m + s]; sB2[m] += sB2[m + s]; }
    __syncthreads();
  }
  if (m == 0) { out[0] = 0.05f * sA[0] / 256.f; out[1] = sB2[0] / 256.f; }
}

extern "C" void kernel_launch(void* const* d_in, const int* in_sizes, int n_in,
                              void* d_out, int out_size, void* d_ws, size_t ws_size,
                              hipStream_t stream) {
  const float* x = (const float*)d_in[0];
  const float* em = (const float*)d_in[1];
  const int* targets = (const int*)d_in[2];
  char* ws = (char*)d_ws;
  unsigned short* em_bf = (unsigned short*)ws;                 // 67108864 B
  unsigned short* x_bf  = (unsigned short*)(ws + 67108864);    // 1048576 B
  float* logits = (float*)(ws + 68157440);                     // 16777216 B
  int*   cnt    = (int*)  (ws + 84934656);                     // 6144 B
  float* topv   = (float*)(ws + 89653248);                     // 6144 B
  int*   topi   = (int*)  (ws + 89659392);                     // 6144 B
  float* lse    = (float*)(ws + 89665536);                     // 1024 B
  float* sa     = (float*)(ws + 89666560);                     // 6144 B

  cvt_kernel<<<dim3(32768), dim3(256), 0, stream>>>(em, em_bf, NEMB * DIMK / 4);
  cvt_kernel<<<dim3(512), dim3(256), 0, stream>>>(x, x_bf, NB * DIMK / 4);
  gemm_kernel<0><<<dim3(128, 4), dim3(256), 0, stream>>>(x_bf, em_bf, (const int*)nullptr,
                                                         logits, (const float*)nullptr,
                                                         (int*)nullptr);
  rowstats_kernel<<<dim3(256), dim3(1024), 0, stream>>>(logits, topv, topi, lse);
  sa_kernel<<<dim3(384), dim3(256), 0, stream>>>(em, topi, sa, cnt);
  gemm_kernel<1><<<dim3(128, 12), dim3(256), 0, stream>>>(em_bf, em_bf, topi,
                                                          (float*)nullptr, sa, cnt);
  final_kernel<<<dim3(1), dim3(256), 0, stream>>>(logits, topv, topi, lse, cnt, targets,
                                                  (float*)d_out);
}

// Round 5
// 487.829 us; speedup vs baseline: 1.0038x; 1.0038x over previous
//
#include <hip/hip_runtime.h>
#include <math.h>

#define DIMK 2048
#define NEMB 16384
#define NB 256
#define NR2 1536          // 256*6 neighbor rows
#define INV_BETA 20.0f
#define NEG_INF (-3.0e38f)

typedef short short8 __attribute__((ext_vector_type(8)));
typedef float f32x4 __attribute__((ext_vector_type(4)));
typedef const __attribute__((address_space(1))) unsigned int* gas_ptr;
typedef __attribute__((address_space(3))) unsigned int* las_ptr;

__device__ __forceinline__ void gl_lds16(const void* g, void* l) {
  __builtin_amdgcn_global_load_lds((gas_ptr)g, (las_ptr)l, 16, 0, 0);
}

__device__ __forceinline__ unsigned short f2bf(float f) {
  unsigned u = __float_as_uint(f);
  u += 0x7fffu + ((u >> 16) & 1u);
  return (unsigned short)(u >> 16);
}

// top-6 insert with (value desc, index asc) tie-break — matches jax top_k order
__device__ __forceinline__ void ins6i(float x, int xi, float v[6], int vi[6]) {
  if (x > v[5] || (x == v[5] && xi < vi[5])) {
    v[5] = x; vi[5] = xi;
#pragma unroll
    for (int j = 5; j > 0; j--) {
      if (v[j] > v[j - 1] || (v[j] == v[j - 1] && vi[j] < vi[j - 1])) {
        float tv = v[j]; v[j] = v[j - 1]; v[j - 1] = tv;
        int ti = vi[j]; vi[j] = vi[j - 1]; vi[j - 1] = ti;
      }
    }
  }
}

__global__ __launch_bounds__(256) void cvt_kernel(const float* __restrict__ src,
                                                  unsigned short* __restrict__ dst, int n4) {
  int i = blockIdx.x * 256 + threadIdx.x;
  if (i < n4) {
    float4 f = ((const float4*)src)[i];
    ushort4 o;
    o.x = f2bf(f.x); o.y = f2bf(f.y); o.z = f2bf(f.z); o.w = f2bf(f.w);
    ((ushort4*)dst)[i] = o;
  }
}

// Staging: NSUB subtiles of [16 rows x 32 k] bf16 (1 KB each), DOUBLE-BUFFERED.
// Fragment-contiguous: chunk for (row=lane&15, kseg=lane>>4) at byte offset lane*16
// -> conflict-free b128 reads.
//
// 2-phase K-loop (T3 minimum recipe): per iter, issue STAGE(k+1 -> buf[nxt]) FIRST,
// then ds_read+MFMA on buf[cur], then ONE __syncthreads() (its vmcnt(0) drain lands
// after the MFMA phase, so the global->LDS latency hides under compute instead of
// being exposed as in the previous stage->drain->compute ordering).
//
// MODE 0: C = X(256xK) * em^T -> logits*20 (fp32 out). tile 64(M)x128(N), grid (128,4)
// MODE 1: C = em[nidx](1536xK) * em^T. NO value output: epilogue directly counts
//         acc > sa[row] per row (exact-count formulation of the recip test) and
//         atomically accumulates into cntOut[1536].
template <int MODE>
__global__ __launch_bounds__(256, 4) void gemm_kernel(
    const unsigned short* __restrict__ Abase, const unsigned short* __restrict__ Bbase,
    const int* __restrict__ nidx, float* __restrict__ outC,
    const float* __restrict__ saIn, int* __restrict__ cntOut) {
  constexpr int MTILE = (MODE == 0) ? 64 : 128;
  constexpr int MI = 4;
  constexpr int NI = (MODE == 0) ? 2 : 4;
  constexpr int NSUB_A = MTILE / 16;   // 4 or 8
  constexpr int NSUB = NSUB_A + 8;     // 12 or 16
  constexpr int NA = NSUB / 4;         // 3 or 4 staging DMAs per wave per k-iter
  constexpr int NK = DIMK / 32;        // 64 k-iterations

  __shared__ unsigned short st[2][NSUB * 512];   // dbuf: 24 KB (MODE0) / 32 KB (MODE1)
  __shared__ int rowIdxSh[128];
  __shared__ float saSh[128];
  __shared__ int cntSh[128];
  int t = threadIdx.x;
  int lane = t & 63, wave = t >> 6;
  int quad = lane >> 4, l16 = lane & 15;
  int wr = (MODE == 0) ? 0 : (wave >> 1);
  int wc = (MODE == 0) ? wave : (wave & 1);
  int bn = blockIdx.x, bm = blockIdx.y;

  if constexpr (MODE == 1) {
    if (t < 128) {
      rowIdxSh[t] = nidx[bm * 128 + t];
      saSh[t] = saIn[bm * 128 + t];
      cntSh[t] = 0;
    }
  }
  __syncthreads();

  const unsigned short* agp[NA];
  int soff[NA];
  {
    int seg = lane >> 4;
#pragma unroll
    for (int a = 0; a < NA; a++) {
      int s = wave + a * 4;
      const unsigned short* basep;
      size_t goff;
      if (s < NSUB_A) {
        int r = s * 16 + l16;
        int grow = (MODE == 0) ? (bm * MTILE + r) : rowIdxSh[r];
        basep = Abase;
        goff = (size_t)grow * DIMK;
      } else {
        int r = (s - NSUB_A) * 16 + l16;
        basep = Bbase;
        goff = (size_t)(bn * 128 + r) * DIMK;
      }
      agp[a] = basep + goff + seg * 8;
      soff[a] = s * 512;               // wave-uniform LDS offset within a buffer
    }
  }

  f32x4 acc[MI][NI];
#pragma unroll
  for (int mi = 0; mi < MI; mi++)
#pragma unroll
    for (int ni = 0; ni < NI; ni++) acc[mi][ni] = (f32x4)0.0f;

  int lo = lane * 8;  // shorts: lane*16 bytes

  // prologue: stage k=0 into buf 0, drain
#pragma unroll
  for (int a = 0; a < NA; a++) gl_lds16(agp[a], &st[0][soff[a]]);
  __syncthreads();

  for (int k = 0; k < NK; k++) {
    int cur = k & 1, nxt = cur ^ 1;
    if (k + 1 < NK) {
#pragma unroll
      for (int a = 0; a < NA; a++) gl_lds16(agp[a] + (k + 1) * 32, &st[nxt][soff[a]]);
    }
    const unsigned short* hb = &st[cur][0];
    short8 af[MI], bfv[NI];
#pragma unroll
    for (int mi = 0; mi < MI; mi++)
      af[mi] = *(const short8*)&hb[(wr * MI + mi) * 512 + lo];
#pragma unroll
    for (int ni = 0; ni < NI; ni++)
      bfv[ni] = *(const short8*)&hb[(NSUB_A + wc * NI + ni) * 512 + lo];
#pragma unroll
    for (int mi = 0; mi < MI; mi++)
#pragma unroll
      for (int ni = 0; ni < NI; ni++)
        acc[mi][ni] =
            __builtin_amdgcn_mfma_f32_16x16x32_bf16(af[mi], bfv[ni], acc[mi][ni], 0, 0, 0);
    __syncthreads();   // drains vmcnt (next buf staged) + all waves' ds_reads of cur done
  }

  if constexpr (MODE == 0) {
#pragma unroll
    for (int mi = 0; mi < MI; mi++) {
      int row = bm * MTILE + mi * 16 + quad * 4;
#pragma unroll
      for (int ni = 0; ni < NI; ni++) {
        int col = bn * 128 + wave * 32 + ni * 16 + l16;
#pragma unroll
        for (int rr = 0; rr < 4; rr++)
          outC[(size_t)(row + rr) * NEMB + col] = acc[mi][ni][rr] * INV_BETA;
      }
    }
  } else {
    // count epilogue: lane holds rows (wr*64+mi*16+quad*4+rr), cols (wc*64+ni*16+l16)
#pragma unroll
    for (int mi = 0; mi < MI; mi++) {
#pragma unroll
      for (int rr = 0; rr < 4; rr++) {
        int rloc = wr * 64 + mi * 16 + quad * 4 + rr;
        float s = saSh[rloc];
        int c = 0;
#pragma unroll
        for (int ni = 0; ni < NI; ni++) c += (acc[mi][ni][rr] > s) ? 1 : 0;
        // reduce over the 16 lanes (l16) sharing this row; stays within quad group
        c += __shfl_xor(c, 1, 64);
        c += __shfl_xor(c, 2, 64);
        c += __shfl_xor(c, 4, 64);
        c += __shfl_xor(c, 8, 64);
        if (l16 == 0) atomicAdd(&cntSh[rloc], c);   // 2 waves (wc) x 4 quads per row
      }
    }
    __syncthreads();
    if (t < 128) atomicAdd(&cntOut[bm * 128 + t], cntSh[t]);
  }
}

// single-pass: per-thread top6(v,i) + two-pass in-register (max, then 16 INDEPENDENT
// exps that pipeline at v_exp throughput), then LDS tree merge.
// 1024 threads/block (16 elems/thread via 4x float4) -> 4 waves/SIMD.
__global__ __launch_bounds__(1024) void rowstats_kernel(
    const float* __restrict__ logits, float* __restrict__ topv,
    int* __restrict__ topi, float* __restrict__ lse) {
  int m = blockIdx.x, t = threadIdx.x;
  const float4* row4 = (const float4*)(logits + (size_t)m * NEMB);
  float v6[6]; int i6[6];
#pragma unroll
  for (int j = 0; j < 6; j++) { v6[j] = NEG_INF; i6[j] = 0x7fffffff; }
  float vals[16];
#pragma unroll
  for (int j = 0; j < 4; j++) {
    float4 f = row4[t + j * 1024];
    vals[j * 4 + 0] = f.x; vals[j * 4 + 1] = f.y;
    vals[j * 4 + 2] = f.z; vals[j * 4 + 3] = f.w;
  }
  float mx = vals[0];
#pragma unroll
  for (int r = 1; r < 16; r++) mx = fmaxf(mx, vals[r]);
  float sme = 0.f;
#pragma unroll
  for (int r = 0; r < 16; r++) sme += expf(vals[r] - mx);   // independent exps
#pragma unroll
  for (int j = 0; j < 4; j++) {
    int base = (t + j * 1024) * 4;
#pragma unroll
    for (int b = 0; b < 4; b++) ins6i(vals[j * 4 + b], base + b, v6, i6);
  }
  __shared__ float sv[1024 * 6]; __shared__ int si[1024 * 6];
  __shared__ float smx[1024], ssm[1024];
#pragma unroll
  for (int j = 0; j < 6; j++) { sv[t * 6 + j] = v6[j]; si[t * 6 + j] = i6[j]; }
  smx[t] = mx; ssm[t] = sme;
  __syncthreads();
  for (int s = 512; s > 0; s >>= 1) {
    if (t < s) {
      float mo = smx[t + s], lo = ssm[t + s];
      float mn = fmaxf(smx[t], mo);
      ssm[t] = ssm[t] * expf(smx[t] - mn) + lo * expf(mo - mn);
      smx[t] = mn;
#pragma unroll
      for (int j = 0; j < 6; j++) ins6i(sv[(t + s) * 6 + j], si[(t + s) * 6 + j], v6, i6);
#pragma unroll
      for (int j = 0; j < 6; j++) { sv[t * 6 + j] = v6[j]; si[t * 6 + j] = i6[j]; }
    }
    __syncthreads();
  }
  if (t == 0) {
    lse[m] = smx[0] + logf(ssm[0]);
#pragma unroll
    for (int j = 0; j < 6; j++) { topv[m * 6 + j] = v6[j]; topi[m * 6 + j] = i6[j]; }
  }
}

// exact fp32 dot: sa[r] = em[topi[r]] . em[anchor(m=r/6)]; also zeroes cnt[r]
__global__ __launch_bounds__(256) void sa_kernel(const float* __restrict__ em,
                                                 const int* __restrict__ topi,
                                                 float* __restrict__ sa,
                                                 int* __restrict__ cnt) {
  int gid = blockIdx.x * 256 + threadIdx.x;
  int w = gid >> 6, lane = gid & 63;
  if (w >= NR2) return;
  if (lane == 1) cnt[w] = 0;
  int m = w / 6;
  int i = topi[w], a = topi[m * 6];
  const float* ei = em + (size_t)i * DIMK;
  const float* ea = em + (size_t)a * DIMK;
  float s = 0.f;
  for (int d = lane; d < DIMK; d += 64) s += ei[d] * ea[d];
#pragma unroll
  for (int off = 32; off > 0; off >>= 1) s += __shfl_down(s, off, 64);
  if (lane == 0) sa[w] = s;
}

// recip[r] == (count of sims values strictly greater than sa[r]) < 6, computed inline
__global__ __launch_bounds__(256) void final_kernel(
    const float* __restrict__ logits, const float* __restrict__ topv,
    const int* __restrict__ topi, const float* __restrict__ lse_arr,
    const int* __restrict__ cnt, const int* __restrict__ targets,
    float* __restrict__ out) {
  int m = threadIdx.x;
  float lse = lse_arr[m];
  int tgt = targets[m];
  float tl = logits[(size_t)m * NEMB + tgt];
  float beta = 0.f, Ps = 0.f, nbp = 0.f;
  bool tin = false;
#pragma unroll
  for (int k = 0; k < 6; k++) {
    int idx = topi[m * 6 + k]; float v = topv[m * 6 + k];
    float p = expf(v - lse);
    if (idx == tgt) { tin = true; beta += (lse - v); Ps += p; }
    else if (cnt[m * 6 + k] < 6) { beta += 0.5f * (lse - v); Ps += p; nbp += p; }
  }
  if (!tin) { beta += (lse - tl); Ps += expf(tl - lse); }
  float alpha = 9.2103404f * (1.f - Ps) + 0.6931472f * nbp;
  __shared__ float sA[256], sB2[256];
  sA[m] = alpha; sB2[m] = beta;
  __syncthreads();
  for (int s = 128; s > 0; s >>= 1) {
    if (m < s) { sA[m] += sA[m + s]; sB2[m] += sB2[m + s]; }
    __syncthreads();
  }
  if (m == 0) { out[0] = 0.05f * sA[0] / 256.f; out[1] = sB2[0] / 256.f; }
}

extern "C" void kernel_launch(void* const* d_in, const int* in_sizes, int n_in,
                              void* d_out, int out_size, void* d_ws, size_t ws_size,
                              hipStream_t stream) {
  const float* x = (const float*)d_in[0];
  const float* em = (const float*)d_in[1];
  const int* targets = (const int*)d_in[2];
  char* ws = (char*)d_ws;
  unsigned short* em_bf = (unsigned short*)ws;                 // 67108864 B
  unsigned short* x_bf  = (unsigned short*)(ws + 67108864);    // 1048576 B
  float* logits = (float*)(ws + 68157440);                     // 16777216 B
  int*   cnt    = (int*)  (ws + 84934656);                     // 6144 B
  float* topv   = (float*)(ws + 89653248);                     // 6144 B
  int*   topi   = (int*)  (ws + 89659392);                     // 6144 B
  float* lse    = (float*)(ws + 89665536);                     // 1024 B
  float* sa     = (float*)(ws + 89666560);                     // 6144 B

  cvt_kernel<<<dim3(32768), dim3(256), 0, stream>>>(em, em_bf, NEMB * DIMK / 4);
  cvt_kernel<<<dim3(512), dim3(256), 0, stream>>>(x, x_bf, NB * DIMK / 4);
  gemm_kernel<0><<<dim3(128, 4), dim3(256), 0, stream>>>(x_bf, em_bf, (const int*)nullptr,
                                                         logits, (const float*)nullptr,
                                                         (int*)nullptr);
  rowstats_kernel<<<dim3(256), dim3(1024), 0, stream>>>(logits, topv, topi, lse);
  sa_kernel<<<dim3(384), dim3(256), 0, stream>>>(em, topi, sa, cnt);
  gemm_kernel<1><<<dim3(128, 12), dim3(256), 0, stream>>>(em_bf, em_bf, topi,
                                                          (float*)nullptr, sa, cnt);
  final_kernel<<<dim3(1), dim3(256), 0, stream>>>(logits, topv, topi, lse, cnt, targets,
                                                  (float*)d_out);
}

// Round 6
// 487.092 us; speedup vs baseline: 1.0053x; 1.0015x over previous
//
#include <hip/hip_runtime.h>
#include <math.h>

#define DIMK 2048
#define NEMB 16384
#define NB 256
#define NR2 1536          // 256*6 neighbor rows
#define INV_BETA 20.0f
#define NEG_INF (-3.0e38f)

typedef short short8 __attribute__((ext_vector_type(8)));
typedef float f32x4 __attribute__((ext_vector_type(4)));
typedef const __attribute__((address_space(1))) unsigned int* gas_ptr;
typedef __attribute__((address_space(3))) unsigned int* las_ptr;

__device__ __forceinline__ void gl_lds16(const void* g, void* l) {
  __builtin_amdgcn_global_load_lds((gas_ptr)g, (las_ptr)l, 16, 0, 0);
}

__device__ __forceinline__ unsigned short f2bf(float f) {
  unsigned u = __float_as_uint(f);
  u += 0x7fffu + ((u >> 16) & 1u);
  return (unsigned short)(u >> 16);
}

// top-6 insert with (value desc, index asc) tie-break — matches jax top_k order
__device__ __forceinline__ void ins6i(float x, int xi, float v[6], int vi[6]) {
  if (x > v[5] || (x == v[5] && xi < vi[5])) {
    v[5] = x; vi[5] = xi;
#pragma unroll
    for (int j = 5; j > 0; j--) {
      if (v[j] > v[j - 1] || (v[j] == v[j - 1] && vi[j] < vi[j - 1])) {
        float tv = v[j]; v[j] = v[j - 1]; v[j - 1] = tv;
        int ti = vi[j]; vi[j] = vi[j - 1]; vi[j - 1] = ti;
      }
    }
  }
}

__global__ __launch_bounds__(256) void cvt_kernel(const float* __restrict__ src,
                                                  unsigned short* __restrict__ dst, int n4) {
  int i = blockIdx.x * 256 + threadIdx.x;
  if (i < n4) {
    float4 f = ((const float4*)src)[i];
    ushort4 o;
    o.x = f2bf(f.x); o.y = f2bf(f.y); o.z = f2bf(f.z); o.w = f2bf(f.w);
    ((ushort4*)dst)[i] = o;
  }
}

// Staging: NSUB subtiles of [16 rows x 32 k] bf16 (1 KB each), TRIPLE-BUFFERED.
// Fragment-contiguous: chunk for (row=lane&15, kseg=lane>>4) at byte offset lane*16
// -> conflict-free b128 reads.
//
// T4 counted-vmcnt schedule (m218/m233: the 2-phase vmcnt(0) drain was the stall;
// counted waits are the isolated +38-73% lever). Steady state keeps 3 tiles of DMAs
// in flight per wave (3*NA); each iter waits only the OLDEST tile via
// s_waitcnt vmcnt(2*NA) — never vmcnt(0) in the main loop. Raw s_barrier (not
// __syncthreads) so the barrier does NOT drain vmcnt. Tile k+3's DMAs get ~3
// iterations of flight (~1500 cyc) — covers L2/HBM-miss latency of the gather.
// vmcnt ledger: in-flight 3*NA steady; tail peels 2*NA -> NA -> 0.
//
// MODE 0: C = X(256xK) * em^T -> logits*20 (fp32 out). tile 64(M)x128(N), grid (128,4)
//         LDS 3x12 KB. NA=3 -> waits vmcnt(6)/(3)/(0).
// MODE 1: C = em[nidx](1536xK) * em^T. NO value output: epilogue directly counts
//         acc > sa[row] per row (exact-count recip test), atomics into cntOut[1536].
//         LDS 3x16 KB (48 KB -> 3 blocks/CU; measured residency was ~3.1 anyway).
//         NA=4 -> waits vmcnt(8)/(4)/(0).
template <int MODE>
__global__ __launch_bounds__(256, 4) void gemm_kernel(
    const unsigned short* __restrict__ Abase, const unsigned short* __restrict__ Bbase,
    const int* __restrict__ nidx, float* __restrict__ outC,
    const float* __restrict__ saIn, int* __restrict__ cntOut) {
  constexpr int MTILE = (MODE == 0) ? 64 : 128;
  constexpr int MI = 4;
  constexpr int NI = (MODE == 0) ? 2 : 4;
  constexpr int NSUB_A = MTILE / 16;   // 4 or 8
  constexpr int NSUB = NSUB_A + 8;     // 12 or 16
  constexpr int NA = NSUB / 4;         // 3 or 4 staging DMAs per wave per tile
  constexpr int NK = DIMK / 32;        // 64 k-iterations

  __shared__ unsigned short st[3][NSUB * 512];   // 36 KB (MODE0) / 48 KB (MODE1)
  __shared__ int rowIdxSh[128];
  __shared__ float saSh[128];
  __shared__ int cntSh[128];
  int t = threadIdx.x;
  int lane = t & 63, wave = t >> 6;
  int quad = lane >> 4, l16 = lane & 15;
  int wr = (MODE == 0) ? 0 : (wave >> 1);
  int wc = (MODE == 0) ? wave : (wave & 1);
  int bn = blockIdx.x, bm = blockIdx.y;

  if constexpr (MODE == 1) {
    if (t < 128) {
      rowIdxSh[t] = nidx[bm * 128 + t];
      saSh[t] = saIn[bm * 128 + t];
      cntSh[t] = 0;
    }
  }
  __syncthreads();

  const unsigned short* agp[NA];
  int soff[NA];
  {
    int seg = lane >> 4;
#pragma unroll
    for (int a = 0; a < NA; a++) {
      int s = wave + a * 4;
      const unsigned short* basep;
      size_t goff;
      if (s < NSUB_A) {
        int r = s * 16 + l16;
        int grow = (MODE == 0) ? (bm * MTILE + r) : rowIdxSh[r];
        basep = Abase;
        goff = (size_t)grow * DIMK;
      } else {
        int r = (s - NSUB_A) * 16 + l16;
        basep = Bbase;
        goff = (size_t)(bn * 128 + r) * DIMK;
      }
      agp[a] = basep + goff + seg * 8;
      soff[a] = s * 512;               // wave-uniform LDS offset within a buffer
    }
  }

  f32x4 acc[MI][NI];
#pragma unroll
  for (int mi = 0; mi < MI; mi++)
#pragma unroll
    for (int ni = 0; ni < NI; ni++) acc[mi][ni] = (f32x4)0.0f;

  int lo = lane * 8;  // shorts: lane*16 bytes

  // prologue: stage tiles 0,1,2 into bufs 0,1,2 (3*NA DMAs per wave in flight)
#pragma unroll
  for (int p = 0; p < 3; p++)
#pragma unroll
    for (int a = 0; a < NA; a++) gl_lds16(agp[a] + p * 32, &st[p][soff[a]]);

  int cur = 0;
  for (int k = 0; k < NK; k++) {
    // wait own tile-k DMAs only (oldest NA of in-flight); NEVER vmcnt(0) mid-loop
    if (k < NK - 2) {
      if constexpr (MODE == 0) asm volatile("s_waitcnt vmcnt(6)" ::: "memory");
      else                     asm volatile("s_waitcnt vmcnt(8)" ::: "memory");
    } else if (k == NK - 2) {
      if constexpr (MODE == 0) asm volatile("s_waitcnt vmcnt(3)" ::: "memory");
      else                     asm volatile("s_waitcnt vmcnt(4)" ::: "memory");
    } else {
      asm volatile("s_waitcnt vmcnt(0)" ::: "memory");
    }
    __builtin_amdgcn_s_barrier();        // all waves' tile-k subtiles visible
    asm volatile("" ::: "memory");       // compiler fence: no LDS-read hoist above

    const unsigned short* hb = &st[cur][0];
    short8 af[MI], bfv[NI];
#pragma unroll
    for (int mi = 0; mi < MI; mi++)
      af[mi] = *(const short8*)&hb[(wr * MI + mi) * 512 + lo];
#pragma unroll
    for (int ni = 0; ni < NI; ni++)
      bfv[ni] = *(const short8*)&hb[(NSUB_A + wc * NI + ni) * 512 + lo];

    asm volatile("s_waitcnt lgkmcnt(0)" ::: "memory");  // own frag reads complete
    __builtin_amdgcn_s_barrier();        // all waves done reading buf[cur]
    asm volatile("" ::: "memory");       // compiler fence: stage stays below

    if (k + 3 < NK) {                    // restage freed buffer with tile k+3
#pragma unroll
      for (int a = 0; a < NA; a++) gl_lds16(agp[a] + (k + 3) * 32, &st[cur][soff[a]]);
    }

#pragma unroll
    for (int mi = 0; mi < MI; mi++)      // MFMA overlaps the fresh DMAs' flight
#pragma unroll
      for (int ni = 0; ni < NI; ni++)
        acc[mi][ni] =
            __builtin_amdgcn_mfma_f32_16x16x32_bf16(af[mi], bfv[ni], acc[mi][ni], 0, 0, 0);

    cur = (cur == 2) ? 0 : cur + 1;
  }

  if constexpr (MODE == 0) {
#pragma unroll
    for (int mi = 0; mi < MI; mi++) {
      int row = bm * MTILE + mi * 16 + quad * 4;
#pragma unroll
      for (int ni = 0; ni < NI; ni++) {
        int col = bn * 128 + wave * 32 + ni * 16 + l16;
#pragma unroll
        for (int rr = 0; rr < 4; rr++)
          outC[(size_t)(row + rr) * NEMB + col] = acc[mi][ni][rr] * INV_BETA;
      }
    }
  } else {
    // count epilogue: lane holds rows (wr*64+mi*16+quad*4+rr), cols (wc*64+ni*16+l16)
#pragma unroll
    for (int mi = 0; mi < MI; mi++) {
#pragma unroll
      for (int rr = 0; rr < 4; rr++) {
        int rloc = wr * 64 + mi * 16 + quad * 4 + rr;
        float s = saSh[rloc];
        int c = 0;
#pragma unroll
        for (int ni = 0; ni < NI; ni++) c += (acc[mi][ni][rr] > s) ? 1 : 0;
        // reduce over the 16 lanes (l16) sharing this row; stays within quad group
        c += __shfl_xor(c, 1, 64);
        c += __shfl_xor(c, 2, 64);
        c += __shfl_xor(c, 4, 64);
        c += __shfl_xor(c, 8, 64);
        if (l16 == 0) atomicAdd(&cntSh[rloc], c);   // 2 waves (wc) x 4 quads per row
      }
    }
    __syncthreads();
    if (t < 128) atomicAdd(&cntOut[bm * 128 + t], cntSh[t]);
  }
}

// single-pass: per-thread top6(v,i) + two-pass in-register (max, then 16 INDEPENDENT
// exps that pipeline at v_exp throughput), then LDS tree merge.
// 1024 threads/block (16 elems/thread via 4x float4) -> 4 waves/SIMD.
__global__ __launch_bounds__(1024) void rowstats_kernel(
    const float* __restrict__ logits, float* __restrict__ topv,
    int* __restrict__ topi, float* __restrict__ lse) {
  int m = blockIdx.x, t = threadIdx.x;
  const float4* row4 = (const float4*)(logits + (size_t)m * NEMB);
  float v6[6]; int i6[6];
#pragma unroll
  for (int j = 0; j < 6; j++) { v6[j] = NEG_INF; i6[j] = 0x7fffffff; }
  float vals[16];
#pragma unroll
  for (int j = 0; j < 4; j++) {
    float4 f = row4[t + j * 1024];
    vals[j * 4 + 0] = f.x; vals[j * 4 + 1] = f.y;
    vals[j * 4 + 2] = f.z; vals[j * 4 + 3] = f.w;
  }
  float mx = vals[0];
#pragma unroll
  for (int r = 1; r < 16; r++) mx = fmaxf(mx, vals[r]);
  float sme = 0.f;
#pragma unroll
  for (int r = 0; r < 16; r++) sme += expf(vals[r] - mx);   // independent exps
#pragma unroll
  for (int j = 0; j < 4; j++) {
    int base = (t + j * 1024) * 4;
#pragma unroll
    for (int b = 0; b < 4; b++) ins6i(vals[j * 4 + b], base + b, v6, i6);
  }
  __shared__ float sv[1024 * 6]; __shared__ int si[1024 * 6];
  __shared__ float smx[1024], ssm[1024];
#pragma unroll
  for (int j = 0; j < 6; j++) { sv[t * 6 + j] = v6[j]; si[t * 6 + j] = i6[j]; }
  smx[t] = mx; ssm[t] = sme;
  __syncthreads();
  for (int s = 512; s > 0; s >>= 1) {
    if (t < s) {
      float mo = smx[t + s], lo = ssm[t + s];
      float mn = fmaxf(smx[t], mo);
      ssm[t] = ssm[t] * expf(smx[t] - mn) + lo * expf(mo - mn);
      smx[t] = mn;
#pragma unroll
      for (int j = 0; j < 6; j++) ins6i(sv[(t + s) * 6 + j], si[(t + s) * 6 + j], v6, i6);
#pragma unroll
      for (int j = 0; j < 6; j++) { sv[t * 6 + j] = v6[j]; si[t * 6 + j] = i6[j]; }
    }
    __syncthreads();
  }
  if (t == 0) {
    lse[m] = smx[0] + logf(ssm[0]);
#pragma unroll
    for (int j = 0; j < 6; j++) { topv[m * 6 + j] = v6[j]; topi[m * 6 + j] = i6[j]; }
  }
}

// exact fp32 dot: sa[r] = em[topi[r]] . em[anchor(m=r/6)]; also zeroes cnt[r]
__global__ __launch_bounds__(256) void sa_kernel(const float* __restrict__ em,
                                                 const int* __restrict__ topi,
                                                 float* __restrict__ sa,
                                                 int* __restrict__ cnt) {
  int gid = blockIdx.x * 256 + threadIdx.x;
  int w = gid >> 6, lane = gid & 63;
  if (w >= NR2) return;
  if (lane == 1) cnt[w] = 0;
  int m = w / 6;
  int i = topi[w], a = topi[m * 6];
  const float* ei = em + (size_t)i * DIMK;
  const float* ea = em + (size_t)a * DIMK;
  float s = 0.f;
  for (int d = lane; d < DIMK; d += 64) s += ei[d] * ea[d];
#pragma unroll
  for (int off = 32; off > 0; off >>= 1) s += __shfl_down(s, off, 64);
  if (lane == 0) sa[w] = s;
}

// recip[r] == (count of sims values strictly greater than sa[r]) < 6, computed inline
__global__ __launch_bounds__(256) void final_kernel(
    const float* __restrict__ logits, const float* __restrict__ topv,
    const int* __restrict__ topi, const float* __restrict__ lse_arr,
    const int* __restrict__ cnt, const int* __restrict__ targets,
    float* __restrict__ out) {
  int m = threadIdx.x;
  float lse = lse_arr[m];
  int tgt = targets[m];
  float tl = logits[(size_t)m * NEMB + tgt];
  float beta = 0.f, Ps = 0.f, nbp = 0.f;
  bool tin = false;
#pragma unroll
  for (int k = 0; k < 6; k++) {
    int idx = topi[m * 6 + k]; float v = topv[m * 6 + k];
    float p = expf(v - lse);
    if (idx == tgt) { tin = true; beta += (lse - v); Ps += p; }
    else if (cnt[m * 6 + k] < 6) { beta += 0.5f * (lse - v); Ps += p; nbp += p; }
  }
  if (!tin) { beta += (lse - tl); Ps += expf(tl - lse); }
  float alpha = 9.2103404f * (1.f - Ps) + 0.6931472f * nbp;
  __shared__ float sA[256], sB2[256];
  sA[m] = alpha; sB2[m] = beta;
  __syncthreads();
  for (int s = 128; s > 0; s >>= 1) {
    if (m < s) { sA[m] += sA[m + s]; sB2[m] += sB2[m + s]; }
    __syncthreads();
  }
  if (m == 0) { out[0] = 0.05f * sA[0] / 256.f; out[1] = sB2[0] / 256.f; }
}

extern "C" void kernel_launch(void* const* d_in, const int* in_sizes, int n_in,
                              void* d_out, int out_size, void* d_ws, size_t ws_size,
                              hipStream_t stream) {
  const float* x = (const float*)d_in[0];
  const float* em = (const float*)d_in[1];
  const int* targets = (const int*)d_in[2];
  char* ws = (char*)d_ws;
  unsigned short* em_bf = (unsigned short*)ws;                 // 67108864 B
  unsigned short* x_bf  = (unsigned short*)(ws + 67108864);    // 1048576 B
  float* logits = (float*)(ws + 68157440);                     // 16777216 B
  int*   cnt    = (int*)  (ws + 84934656);                     // 6144 B
  float* topv   = (float*)(ws + 89653248);                     // 6144 B
  int*   topi   = (int*)  (ws + 89659392);                     // 6144 B
  float* lse    = (float*)(ws + 89665536);                     // 1024 B
  float* sa     = (float*)(ws + 89666560);                     // 6144 B

  cvt_kernel<<<dim3(32768), dim3(256), 0, stream>>>(em, em_bf, NEMB * DIMK / 4);
  cvt_kernel<<<dim3(512), dim3(256), 0, stream>>>(x, x_bf, NB * DIMK / 4);
  gemm_kernel<0><<<dim3(128, 4), dim3(256), 0, stream>>>(x_bf, em_bf, (const int*)nullptr,
                                                         logits, (const float*)nullptr,
                                                         (int*)nullptr);
  rowstats_kernel<<<dim3(256), dim3(1024), 0, stream>>>(logits, topv, topi, lse);
  sa_kernel<<<dim3(384), dim3(256), 0, stream>>>(em, topi, sa, cnt);
  gemm_kernel<1><<<dim3(128, 12), dim3(256), 0, stream>>>(em_bf, em_bf, topi,
                                                          (float*)nullptr, sa, cnt);
  final_kernel<<<dim3(1), dim3(256), 0, stream>>>(logits, topv, topi, lse, cnt, targets,
                                                  (float*)d_out);
}

// Round 7
// 471.035 us; speedup vs baseline: 1.0396x; 1.0341x over previous
//
#include <hip/hip_runtime.h>
#include <math.h>

#define DIMK 2048
#define NEMB 16384
#define NB 256
#define NR2 1536          // 256*6 neighbor rows
#define INV_BETA 20.0f
#define NEG_INF (-3.0e38f)

typedef short short8 __attribute__((ext_vector_type(8)));
typedef float f32x4 __attribute__((ext_vector_type(4)));
typedef const __attribute__((address_space(1))) unsigned int* gas_ptr;
typedef __attribute__((address_space(3))) unsigned int* las_ptr;

__device__ __forceinline__ void gl_lds16(const void* g, void* l) {
  __builtin_amdgcn_global_load_lds((gas_ptr)g, (las_ptr)l, 16, 0, 0);
}

// inline-asm LDS read: OPAQUE to the compiler's waitcnt pass, so it cannot insert
// s_waitcnt vmcnt(0) before it on behalf of in-flight global_load_lds (the R2-R6
// stall: plain C ds_reads got a compiler vmcnt(0) drain every iter). Rule #18:
// every use is followed by lgkmcnt(0) + sched_barrier(0) before dependent MFMA.
__device__ __forceinline__ short8 dsr(const void* p) {
  short8 r;
  asm volatile("ds_read_b128 %0, %1"
               : "=&v"(r)
               : "v"((const __attribute__((address_space(3))) unsigned short*)p));
  return r;
}

#define LGKM0_FENCE                                          \
  do {                                                       \
    asm volatile("s_waitcnt lgkmcnt(0)" ::: "memory");       \
    __builtin_amdgcn_sched_barrier(0);                       \
  } while (0)

__device__ __forceinline__ unsigned short f2bf(float f) {
  unsigned u = __float_as_uint(f);
  u += 0x7fffu + ((u >> 16) & 1u);
  return (unsigned short)(u >> 16);
}

// top-6 insert with (value desc, index asc) tie-break — matches jax top_k order
__device__ __forceinline__ void ins6i(float x, int xi, float v[6], int vi[6]) {
  if (x > v[5] || (x == v[5] && xi < vi[5])) {
    v[5] = x; vi[5] = xi;
#pragma unroll
    for (int j = 5; j > 0; j--) {
      if (v[j] > v[j - 1] || (v[j] == v[j - 1] && vi[j] < vi[j - 1])) {
        float tv = v[j]; v[j] = v[j - 1]; v[j - 1] = tv;
        int ti = vi[j]; vi[j] = vi[j - 1]; vi[j - 1] = ti;
      }
    }
  }
}

__global__ __launch_bounds__(256) void cvt_kernel(const float* __restrict__ src,
                                                  unsigned short* __restrict__ dst, int n4) {
  int i = blockIdx.x * 256 + threadIdx.x;
  if (i < n4) {
    float4 f = ((const float4*)src)[i];
    ushort4 o;
    o.x = f2bf(f.x); o.y = f2bf(f.y); o.z = f2bf(f.z); o.w = f2bf(f.w);
    ((ushort4*)dst)[i] = o;
  }
}

// ---------------- gemm0: logits = X(256xK) @ em^T * 20 -----------------
// R6's verified MODE0 path, de-templated, byte-equivalent. tile 64x128, grid (128,4).
__global__ __launch_bounds__(256, 4) void gemm0_kernel(
    const unsigned short* __restrict__ Abase, const unsigned short* __restrict__ Bbase,
    float* __restrict__ outC) {
  constexpr int MI = 4, NI = 2, NSUB_A = 4, NSUB = 12, NA = 3, NK = DIMK / 32;
  __shared__ unsigned short st[3][NSUB * 512];
  int t = threadIdx.x;
  int lane = t & 63, wave = t >> 6;
  int quad = lane >> 4, l16 = lane & 15;
  int wc = wave;
  int bn = blockIdx.x, bm = blockIdx.y;

  const unsigned short* agp[NA];
  int soff[NA];
  {
    int seg = lane >> 4;
#pragma unroll
    for (int a = 0; a < NA; a++) {
      int s = wave + a * 4;
      size_t goff;
      const unsigned short* basep;
      if (s < NSUB_A) {
        basep = Abase;
        goff = (size_t)(bm * 64 + s * 16 + l16) * DIMK;
      } else {
        basep = Bbase;
        goff = (size_t)(bn * 128 + (s - NSUB_A) * 16 + l16) * DIMK;
      }
      agp[a] = basep + goff + seg * 8;
      soff[a] = s * 512;
    }
  }

  f32x4 acc[MI][NI];
#pragma unroll
  for (int mi = 0; mi < MI; mi++)
#pragma unroll
    for (int ni = 0; ni < NI; ni++) acc[mi][ni] = (f32x4)0.0f;

  int lo = lane * 8;
#pragma unroll
  for (int p = 0; p < 3; p++)
#pragma unroll
    for (int a = 0; a < NA; a++) gl_lds16(agp[a] + p * 32, &st[p][soff[a]]);

  int cur = 0;
  for (int k = 0; k < NK; k++) {
    if (k < NK - 2)      asm volatile("s_waitcnt vmcnt(6)" ::: "memory");
    else if (k == NK - 2) asm volatile("s_waitcnt vmcnt(3)" ::: "memory");
    else                 asm volatile("s_waitcnt vmcnt(0)" ::: "memory");
    __builtin_amdgcn_s_barrier();
    asm volatile("" ::: "memory");
    const unsigned short* hb = &st[cur][0];
    short8 af[MI], bfv[NI];
#pragma unroll
    for (int mi = 0; mi < MI; mi++) af[mi] = *(const short8*)&hb[mi * 512 + lo];
#pragma unroll
    for (int ni = 0; ni < NI; ni++)
      bfv[ni] = *(const short8*)&hb[(NSUB_A + wc * NI + ni) * 512 + lo];
    asm volatile("s_waitcnt lgkmcnt(0)" ::: "memory");
    __builtin_amdgcn_s_barrier();
    asm volatile("" ::: "memory");
    if (k + 3 < NK) {
#pragma unroll
      for (int a = 0; a < NA; a++) gl_lds16(agp[a] + (k + 3) * 32, &st[cur][soff[a]]);
    }
#pragma unroll
    for (int mi = 0; mi < MI; mi++)
#pragma unroll
      for (int ni = 0; ni < NI; ni++)
        acc[mi][ni] =
            __builtin_amdgcn_mfma_f32_16x16x32_bf16(af[mi], bfv[ni], acc[mi][ni], 0, 0, 0);
    cur = (cur == 2) ? 0 : cur + 1;
  }

#pragma unroll
  for (int mi = 0; mi < MI; mi++) {
    int row = bm * 64 + mi * 16 + quad * 4;
#pragma unroll
    for (int ni = 0; ni < NI; ni++) {
      int col = bn * 128 + wave * 32 + ni * 16 + l16;
#pragma unroll
      for (int rr = 0; rr < 4; rr++)
        outC[(size_t)(row + rr) * NEMB + col] = acc[mi][ni][rr] * INV_BETA;
    }
  }
}

// ---------------- gemm1: count of (em[nidx] @ em^T > sa[row]) ----------------
// 8-phase-class rewrite: BM=256 x BN=128, BK=64, 512 thr = 8 waves (2M x 4N),
// per-wave 128x32 (MI=8, NI=2). LDS: 3-deep pipeline x (2 k-halves x 24 subtiles
// x 1KB) = 144 KB, fragment-contiguous subtiles (0 bank conflicts).
// Counted vmcnt(12/6/0) + raw s_barrier + INLINE-ASM ds_read (opaque to the
// waitcnt pass) + lgkmcnt fences; 4 MFMA phases of 8, reads of phase p+1 issued
// before MFMAs of phase p; setprio(1) around MFMA clusters (T5); stage of tile
// k+3 after barrier2 overlaps P3. Grid (128,6) = 768 = 3 full CU-waves.
__global__ __launch_bounds__(512, 2) void gemm1_kernel(
    const unsigned short* __restrict__ em_bf, const int* __restrict__ nidx,
    const float* __restrict__ saIn, int* __restrict__ cntOut) {
  __shared__ unsigned short st[3][2][24 * 512];   // 144 KiB
  __shared__ int rowIdxSh[256];
  __shared__ float saSh[256];
  __shared__ int cntSh[256];
  int t = threadIdx.x;
  int lane = t & 63, wave = t >> 6;
  int quad = lane >> 4, l16 = lane & 15;
  int wr = wave >> 2, wc = wave & 3;
  int bn = blockIdx.x, bm = blockIdx.y;

  if (t < 256) {
    rowIdxSh[t] = nidx[bm * 256 + t];
    saSh[t] = saIn[bm * 256 + t];
    cntSh[t] = 0;
  }
  __syncthreads();

  // 6 DMAs/wave/K-tile: a = h*3+j -> subtile s = wave + j*8 (A: s<16, B: s>=16),
  // k-half h. Subtile layout [16 rows x 32 k], lane: row=l16, 8-short seg=lane>>4.
  const unsigned short* agp[6];
  unsigned ldsoff[6];
  {
    int seg = lane >> 4;
#pragma unroll
    for (int a = 0; a < 6; a++) {
      int j = a % 3, h = a / 3;
      int s = wave + j * 8;
      size_t grow;
      if (s < 16) grow = (size_t)rowIdxSh[s * 16 + l16];
      else        grow = (size_t)(bn * 128 + (s - 16) * 16 + l16);
      agp[a] = em_bf + grow * DIMK + h * 32 + seg * 8;
      ldsoff[a] = (unsigned)(h * 24576 + s * 1024);
    }
  }

  f32x4 acc[8][2];
#pragma unroll
  for (int mi = 0; mi < 8; mi++)
#pragma unroll
    for (int ni = 0; ni < 2; ni++) acc[mi][ni] = (f32x4)0.0f;

  char* stb = (char*)&st[0][0][0];
  unsigned aoffA = (unsigned)((wr * 8) * 1024 + lane * 16);
  unsigned aoffB = (unsigned)((16 + wc * 2) * 1024 + lane * 16);

  // prologue: tiles 0,1,2 into bufs 0,1,2 (18 DMAs/wave in flight)
#pragma unroll
  for (int p = 0; p < 3; p++)
#pragma unroll
    for (int a = 0; a < 6; a++)
      gl_lds16(agp[a] + p * 64, stb + p * 49152 + ldsoff[a]);

  unsigned curoff = 0;
  for (int k = 0; k < 32; k++) {
    if (k < 30)       asm volatile("s_waitcnt vmcnt(12)" ::: "memory");
    else if (k == 30) asm volatile("s_waitcnt vmcnt(6)" ::: "memory");
    else              asm volatile("s_waitcnt vmcnt(0)" ::: "memory");
    __builtin_amdgcn_s_barrier();       // all waves' tile-k subtiles in LDS
    __builtin_amdgcn_sched_barrier(0);
    const char* cb = stb + curoff;

    // R0: all B frags + A mi0,1 (8 reads)
    short8 b00 = dsr(cb + aoffB);
    short8 b10 = dsr(cb + aoffB + 1024);
    short8 b01 = dsr(cb + aoffB + 24576);
    short8 b11 = dsr(cb + aoffB + 25600);
    short8 a00 = dsr(cb + aoffA);
    short8 a01 = dsr(cb + aoffA + 24576);
    short8 a10 = dsr(cb + aoffA + 1024);
    short8 a11 = dsr(cb + aoffA + 25600);
    LGKM0_FENCE;
    // R1 (background under P0): A mi2,3
    short8 a20 = dsr(cb + aoffA + 2048);
    short8 a21 = dsr(cb + aoffA + 26624);
    short8 a30 = dsr(cb + aoffA + 3072);
    short8 a31 = dsr(cb + aoffA + 27648);
    __builtin_amdgcn_s_setprio(1);
    acc[0][0] = __builtin_amdgcn_mfma_f32_16x16x32_bf16(a00, b00, acc[0][0], 0, 0, 0);
    acc[0][0] = __builtin_amdgcn_mfma_f32_16x16x32_bf16(a01, b01, acc[0][0], 0, 0, 0);
    acc[0][1] = __builtin_amdgcn_mfma_f32_16x16x32_bf16(a00, b10, acc[0][1], 0, 0, 0);
    acc[0][1] = __builtin_amdgcn_mfma_f32_16x16x32_bf16(a01, b11, acc[0][1], 0, 0, 0);
    acc[1][0] = __builtin_amdgcn_mfma_f32_16x16x32_bf16(a10, b00, acc[1][0], 0, 0, 0);
    acc[1][0] = __builtin_amdgcn_mfma_f32_16x16x32_bf16(a11, b01, acc[1][0], 0, 0, 0);
    acc[1][1] = __builtin_amdgcn_mfma_f32_16x16x32_bf16(a10, b10, acc[1][1], 0, 0, 0);
    acc[1][1] = __builtin_amdgcn_mfma_f32_16x16x32_bf16(a11, b11, acc[1][1], 0, 0, 0);
    __builtin_amdgcn_s_setprio(0);
    LGKM0_FENCE;
    // R2 under P1: A mi4,5
    short8 a40 = dsr(cb + aoffA + 4096);
    short8 a41 = dsr(cb + aoffA + 28672);
    short8 a50 = dsr(cb + aoffA + 5120);
    short8 a51 = dsr(cb + aoffA + 29696);
    __builtin_amdgcn_s_setprio(1);
    acc[2][0] = __builtin_amdgcn_mfma_f32_16x16x32_bf16(a20, b00, acc[2][0], 0, 0, 0);
    acc[2][0] = __builtin_amdgcn_mfma_f32_16x16x32_bf16(a21, b01, acc[2][0], 0, 0, 0);
    acc[2][1] = __builtin_amdgcn_mfma_f32_16x16x32_bf16(a20, b10, acc[2][1], 0, 0, 0);
    acc[2][1] = __builtin_amdgcn_mfma_f32_16x16x32_bf16(a21, b11, acc[2][1], 0, 0, 0);
    acc[3][0] = __builtin_amdgcn_mfma_f32_16x16x32_bf16(a30, b00, acc[3][0], 0, 0, 0);
    acc[3][0] = __builtin_amdgcn_mfma_f32_16x16x32_bf16(a31, b01, acc[3][0], 0, 0, 0);
    acc[3][1] = __builtin_amdgcn_mfma_f32_16x16x32_bf16(a30, b10, acc[3][1], 0, 0, 0);
    acc[3][1] = __builtin_amdgcn_mfma_f32_16x16x32_bf16(a31, b11, acc[3][1], 0, 0, 0);
    __builtin_amdgcn_s_setprio(0);
    LGKM0_FENCE;
    // R3 under P2: A mi6,7
    short8 a60 = dsr(cb + aoffA + 6144);
    short8 a61 = dsr(cb + aoffA + 30720);
    short8 a70 = dsr(cb + aoffA + 7168);
    short8 a71 = dsr(cb + aoffA + 31744);
    __builtin_amdgcn_s_setprio(1);
    acc[4][0] = __builtin_amdgcn_mfma_f32_16x16x32_bf16(a40, b00, acc[4][0], 0, 0, 0);
    acc[4][0] = __builtin_amdgcn_mfma_f32_16x16x32_bf16(a41, b01, acc[4][0], 0, 0, 0);
    acc[4][1] = __builtin_amdgcn_mfma_f32_16x16x32_bf16(a40, b10, acc[4][1], 0, 0, 0);
    acc[4][1] = __builtin_amdgcn_mfma_f32_16x16x32_bf16(a41, b11, acc[4][1], 0, 0, 0);
    acc[5][0] = __builtin_amdgcn_mfma_f32_16x16x32_bf16(a50, b00, acc[5][0], 0, 0, 0);
    acc[5][0] = __builtin_amdgcn_mfma_f32_16x16x32_bf16(a51, b01, acc[5][0], 0, 0, 0);
    acc[5][1] = __builtin_amdgcn_mfma_f32_16x16x32_bf16(a50, b10, acc[5][1], 0, 0, 0);
    acc[5][1] = __builtin_amdgcn_mfma_f32_16x16x32_bf16(a51, b11, acc[5][1], 0, 0, 0);
    __builtin_amdgcn_s_setprio(0);
    LGKM0_FENCE;                         // all 20 reads of buf[cur] complete
    __builtin_amdgcn_s_barrier();        // all waves done reading buf[cur]
    __builtin_amdgcn_sched_barrier(0);
    if (k < 29) {                        // restage freed buf with tile k+3
      char* sb = stb + curoff;
#pragma unroll
      for (int a = 0; a < 6; a++)
        gl_lds16(agp[a] + (size_t)(k + 3) * 64, sb + ldsoff[a]);
    }
    __builtin_amdgcn_s_setprio(1);       // P3 overlaps the fresh DMAs' flight
    acc[6][0] = __builtin_amdgcn_mfma_f32_16x16x32_bf16(a60, b00, acc[6][0], 0, 0, 0);
    acc[6][0] = __builtin_amdgcn_mfma_f32_16x16x32_bf16(a61, b01, acc[6][0], 0, 0, 0);
    acc[6][1] = __builtin_amdgcn_mfma_f32_16x16x32_bf16(a60, b10, acc[6][1], 0, 0, 0);
    acc[6][1] = __builtin_amdgcn_mfma_f32_16x16x32_bf16(a61, b11, acc[6][1], 0, 0, 0);
    acc[7][0] = __builtin_amdgcn_mfma_f32_16x16x32_bf16(a70, b00, acc[7][0], 0, 0, 0);
    acc[7][0] = __builtin_amdgcn_mfma_f32_16x16x32_bf16(a71, b01, acc[7][0], 0, 0, 0);
    acc[7][1] = __builtin_amdgcn_mfma_f32_16x16x32_bf16(a70, b10, acc[7][1], 0, 0, 0);
    acc[7][1] = __builtin_amdgcn_mfma_f32_16x16x32_bf16(a71, b11, acc[7][1], 0, 0, 0);
    __builtin_amdgcn_s_setprio(0);
    curoff = (curoff == 98304u) ? 0u : curoff + 49152u;
  }

  // count epilogue: row rloc = wr*128+mi*16+quad*4+rr; cols wc*32+ni*16+l16
#pragma unroll
  for (int mi = 0; mi < 8; mi++) {
#pragma unroll
    for (int rr = 0; rr < 4; rr++) {
      int rloc = wr * 128 + mi * 16 + quad * 4 + rr;
      float s = saSh[rloc];
      int c = ((acc[mi][0][rr] > s) ? 1 : 0) + ((acc[mi][1][rr] > s) ? 1 : 0);
      c += __shfl_xor(c, 1, 64);
      c += __shfl_xor(c, 2, 64);
      c += __shfl_xor(c, 4, 64);
      c += __shfl_xor(c, 8, 64);
      if (l16 == 0) atomicAdd(&cntSh[rloc], c);   // 4 wc-waves x 4 quads per row
    }
  }
  __syncthreads();
  if (t < 256) atomicAdd(&cntOut[bm * 256 + t], cntSh[t]);
}

// single-pass: per-thread top6(v,i) + two-pass in-register softmax stats,
// then LDS tree merge. 1024 threads/block (16 elems/thread via 4x float4).
__global__ __launch_bounds__(1024) void rowstats_kernel(
    const float* __restrict__ logits, float* __restrict__ topv,
    int* __restrict__ topi, float* __restrict__ lse) {
  int m = blockIdx.x, t = threadIdx.x;
  const float4* row4 = (const float4*)(logits + (size_t)m * NEMB);
  float v6[6]; int i6[6];
#pragma unroll
  for (int j = 0; j < 6; j++) { v6[j] = NEG_INF; i6[j] = 0x7fffffff; }
  float vals[16];
#pragma unroll
  for (int j = 0; j < 4; j++) {
    float4 f = row4[t + j * 1024];
    vals[j * 4 + 0] = f.x; vals[j * 4 + 1] = f.y;
    vals[j * 4 + 2] = f.z; vals[j * 4 + 3] = f.w;
  }
  float mx = vals[0];
#pragma unroll
  for (int r = 1; r < 16; r++) mx = fmaxf(mx, vals[r]);
  float sme = 0.f;
#pragma unroll
  for (int r = 0; r < 16; r++) sme += expf(vals[r] - mx);
#pragma unroll
  for (int j = 0; j < 4; j++) {
    int base = (t + j * 1024) * 4;
#pragma unroll
    for (int b = 0; b < 4; b++) ins6i(vals[j * 4 + b], base + b, v6, i6);
  }
  __shared__ float sv[1024 * 6]; __shared__ int si[1024 * 6];
  __shared__ float smx[1024], ssm[1024];
#pragma unroll
  for (int j = 0; j < 6; j++) { sv[t * 6 + j] = v6[j]; si[t * 6 + j] = i6[j]; }
  smx[t] = mx; ssm[t] = sme;
  __syncthreads();
  for (int s = 512; s > 0; s >>= 1) {
    if (t < s) {
      float mo = smx[t + s], lo = ssm[t + s];
      float mn = fmaxf(smx[t], mo);
      ssm[t] = ssm[t] * expf(smx[t] - mn) + lo * expf(mo - mn);
      smx[t] = mn;
#pragma unroll
      for (int j = 0; j < 6; j++) ins6i(sv[(t + s) * 6 + j], si[(t + s) * 6 + j], v6, i6);
#pragma unroll
      for (int j = 0; j < 6; j++) { sv[t * 6 + j] = v6[j]; si[t * 6 + j] = i6[j]; }
    }
    __syncthreads();
  }
  if (t == 0) {
    lse[m] = smx[0] + logf(ssm[0]);
#pragma unroll
    for (int j = 0; j < 6; j++) { topv[m * 6 + j] = v6[j]; topi[m * 6 + j] = i6[j]; }
  }
}

// exact fp32 dot: sa[r] = em[topi[r]] . em[anchor(m=r/6)]; also zeroes cnt[r]
__global__ __launch_bounds__(256) void sa_kernel(const float* __restrict__ em,
                                                 const int* __restrict__ topi,
                                                 float* __restrict__ sa,
                                                 int* __restrict__ cnt) {
  int gid = blockIdx.x * 256 + threadIdx.x;
  int w = gid >> 6, lane = gid & 63;
  if (w >= NR2) return;
  if (lane == 1) cnt[w] = 0;
  int m = w / 6;
  int i = topi[w], a = topi[m * 6];
  const float* ei = em + (size_t)i * DIMK;
  const float* ea = em + (size_t)a * DIMK;
  float s = 0.f;
  for (int d = lane; d < DIMK; d += 64) s += ei[d] * ea[d];
#pragma unroll
  for (int off = 32; off > 0; off >>= 1) s += __shfl_down(s, off, 64);
  if (lane == 0) sa[w] = s;
}

// recip[r] == (count of sims values strictly greater than sa[r]) < 6
__global__ __launch_bounds__(256) void final_kernel(
    const float* __restrict__ logits, const float* __restrict__ topv,
    const int* __restrict__ topi, const float* __restrict__ lse_arr,
    const int* __restrict__ cnt, const int* __restrict__ targets,
    float* __restrict__ out) {
  int m = threadIdx.x;
  float lse = lse_arr[m];
  int tgt = targets[m];
  float tl = logits[(size_t)m * NEMB + tgt];
  float beta = 0.f, Ps = 0.f, nbp = 0.f;
  bool tin = false;
#pragma unroll
  for (int k = 0; k < 6; k++) {
    int idx = topi[m * 6 + k]; float v = topv[m * 6 + k];
    float p = expf(v - lse);
    if (idx == tgt) { tin = true; beta += (lse - v); Ps += p; }
    else if (cnt[m * 6 + k] < 6) { beta += 0.5f * (lse - v); Ps += p; nbp += p; }
  }
  if (!tin) { beta += (lse - tl); Ps += expf(tl - lse); }
  float alpha = 9.2103404f * (1.f - Ps) + 0.6931472f * nbp;
  __shared__ float sA[256], sB2[256];
  sA[m] = alpha; sB2[m] = beta;
  __syncthreads();
  for (int s = 128; s > 0; s >>= 1) {
    if (m < s) { sA[m] += sA[m + s]; sB2[m] += sB2[m + s]; }
    __syncthreads();
  }
  if (m == 0) { out[0] = 0.05f * sA[0] / 256.f; out[1] = sB2[0] / 256.f; }
}

extern "C" void kernel_launch(void* const* d_in, const int* in_sizes, int n_in,
                              void* d_out, int out_size, void* d_ws, size_t ws_size,
                              hipStream_t stream) {
  const float* x = (const float*)d_in[0];
  const float* em = (const float*)d_in[1];
  const int* targets = (const int*)d_in[2];
  char* ws = (char*)d_ws;
  unsigned short* em_bf = (unsigned short*)ws;                 // 67108864 B
  unsigned short* x_bf  = (unsigned short*)(ws + 67108864);    // 1048576 B
  float* logits = (float*)(ws + 68157440);                     // 16777216 B
  int*   cnt    = (int*)  (ws + 84934656);                     // 6144 B
  float* topv   = (float*)(ws + 89653248);                     // 6144 B
  int*   topi   = (int*)  (ws + 89659392);                     // 6144 B
  float* lse    = (float*)(ws + 89665536);                     // 1024 B
  float* sa     = (float*)(ws + 89666560);                     // 6144 B

  cvt_kernel<<<dim3(32768), dim3(256), 0, stream>>>(em, em_bf, NEMB * DIMK / 4);
  cvt_kernel<<<dim3(512), dim3(256), 0, stream>>>(x, x_bf, NB * DIMK / 4);
  gemm0_kernel<<<dim3(128, 4), dim3(256), 0, stream>>>(x_bf, em_bf, logits);
  rowstats_kernel<<<dim3(256), dim3(1024), 0, stream>>>(logits, topv, topi, lse);
  sa_kernel<<<dim3(384), dim3(256), 0, stream>>>(em, topi, sa, cnt);
  gemm1_kernel<<<dim3(128, 6), dim3(512), 0, stream>>>(em_bf, topi, sa, cnt);
  final_kernel<<<dim3(1), dim3(256), 0, stream>>>(logits, topv, topi, lse, cnt, targets,
                                                  (float*)d_out);
}

// Round 9
// 409.859 us; speedup vs baseline: 1.1947x; 1.1493x over previous
//
#include <hip/hip_runtime.h>
#include <math.h>

#define DIMK 2048
#define NEMB 16384
#define NB 256
#define NR2 1536          // 256*6 neighbor rows
#define INV_BETA 20.0f
#define NEG_INF (-3.0e38f)

typedef short short8 __attribute__((ext_vector_type(8)));
typedef float f32x4 __attribute__((ext_vector_type(4)));

__device__ __forceinline__ unsigned short f2bf(float f) {
  unsigned u = __float_as_uint(f);
  u += 0x7fffu + ((u >> 16) & 1u);
  return (unsigned short)(u >> 16);
}

// top-6 insert with (value desc, index asc) tie-break — matches jax top_k order
__device__ __forceinline__ void ins6i(float x, int xi, float v[6], int vi[6]) {
  if (x > v[5] || (x == v[5] && xi < vi[5])) {
    v[5] = x; vi[5] = xi;
#pragma unroll
    for (int j = 5; j > 0; j--) {
      if (v[j] > v[j - 1] || (v[j] == v[j - 1] && vi[j] < vi[j - 1])) {
        float tv = v[j]; v[j] = v[j - 1]; v[j - 1] = tv;
        int ti = vi[j]; vi[j] = vi[j - 1]; vi[j - 1] = ti;
      }
    }
  }
}

__global__ __launch_bounds__(256) void cvt_kernel(const float* __restrict__ src,
                                                  unsigned short* __restrict__ dst, int n4) {
  int i = blockIdx.x * 256 + threadIdx.x;
  if (i < n4) {
    float4 f = ((const float4*)src)[i];
    ushort4 o;
    o.x = f2bf(f.x); o.y = f2bf(f.y); o.z = f2bf(f.z); o.w = f2bf(f.w);
    ((ushort4*)dst)[i] = o;
  }
}

// ---------------- reg-staged GEMM template (T14: global->VGPR->ds_write) ----------------
// NO global_load_lds, NO inline asm. Loads for tile k+2 issue at the top of each step
// (a full compute phase of flight); compiler inserts fine-grained vmcnt before the
// dependent ds_write (VGPR dep — no conservative LDS-alias drain possible).
// LDS: double-buffered NSUB subtiles of [16 rows x 32 k] bf16, fragment-contiguous
// (1 KB each; both b128 reads and writes are lane-contiguous -> conflict-free).
//
// MODE 0: logits = X(256xK) @ em^T * 20. tile 64x128, grid (128,4).
// MODE 1: count prefilter — rows = em[nidx[0..1536)], cols [0, 2048). tile 128x128,
//         grid (16,12). Epilogue counts acc > sa[row], atomics into cntOut.
// MODE 2: count finish — only survivor rows (cnt<6 after phase A), cols [2048,16384).
//         grid (112,12); blocks with bq*128 >= nsurv exit immediately.
//         Early-exit is EXACT: count>=6 is monotone -> recip=0 final; survivors get
//         the complete count.
template <int MODE>
__global__ __launch_bounds__(256, 3) void gemm_rs(
    const unsigned short* __restrict__ Abase, const unsigned short* __restrict__ Bbase,
    const int* __restrict__ nidx, float* __restrict__ outC,
    const float* __restrict__ saIn, int* __restrict__ cntOut,
    const int* __restrict__ surv, const int* __restrict__ nsurvp) {
  constexpr int MTILE = (MODE == 0) ? 64 : 128;
  constexpr int MI = 4;
  constexpr int NI = (MODE == 0) ? 2 : 4;
  constexpr int NSUB_A = MTILE / 16;   // 4 or 8
  constexpr int NSUB = NSUB_A + 8;     // 12 or 16
  constexpr int NA = NSUB / 4;         // 3 or 4 subtiles staged per wave per k-iter
  constexpr int NK = DIMK / 32;        // 64

  __shared__ unsigned short st[2][NSUB * 512];   // 24 KB (MODE0) / 32 KB dbuf
  __shared__ int rowIdxSh[128];
  __shared__ float saSh[128];
  __shared__ int cntSh[128];
  __shared__ int outRowSh[128];
  int t = threadIdx.x;
  int lane = t & 63, wave = t >> 6;
  int quad = lane >> 4, l16 = lane & 15;
  int wr = (MODE == 0) ? 0 : (wave >> 1);
  int wc = (MODE == 0) ? wave : (wave & 1);
  int bn = blockIdx.x, bm = blockIdx.y;
  int nvalid = 128;

  if constexpr (MODE == 2) {
    int ns = nsurvp[0];
    if (bm * 128 >= ns) return;        // uniform per-block: before any barrier
    nvalid = (ns - bm * 128 < 128) ? (ns - bm * 128) : 128;
  }
  if constexpr (MODE >= 1) {
    if (t < 128) {
      int r;
      if constexpr (MODE == 1) r = bm * 128 + t;
      else r = surv[bm * 128 + ((t < nvalid) ? t : 0)];   // pad rows dup row 0
      rowIdxSh[t] = nidx[r];
      saSh[t] = saIn[r];
      cntSh[t] = 0;
      outRowSh[t] = r;
    }
    __syncthreads();
  }

  int colbase = (MODE == 2) ? ((bn + 16) * 128) : (bn * 128);

  const unsigned short* agp[NA];
  int soff[NA];
  {
    int seg = lane >> 4;
#pragma unroll
    for (int a = 0; a < NA; a++) {
      int s = wave + a * 4;
      size_t grow;
      const unsigned short* basep;
      if (s < NSUB_A) {
        int r = s * 16 + l16;
        grow = (MODE == 0) ? (size_t)(bm * MTILE + r) : (size_t)rowIdxSh[r];
        basep = Abase;
      } else {
        grow = (size_t)(colbase + (s - NSUB_A) * 16 + l16);
        basep = Bbase;
      }
      agp[a] = basep + grow * DIMK + seg * 8;
      soff[a] = s * 512;               // subtile base (shorts) within a buffer
    }
  }

  f32x4 acc[MI][NI];
#pragma unroll
  for (int mi = 0; mi < MI; mi++)
#pragma unroll
    for (int ni = 0; ni < NI; ni++) acc[mi][ni] = (f32x4)0.0f;

  int lo = lane * 8;  // shorts: lane*16 bytes

  short8 rA[NA], rB2[NA];
  auto LOADT = [&](short8* R, int kk) {
#pragma unroll
    for (int a = 0; a < NA; a++) R[a] = *(const short8*)(agp[a] + kk * 32);
  };
  auto WRITET = [&](const short8* R, int b) {
#pragma unroll
    for (int a = 0; a < NA; a++) *(short8*)&st[b][soff[a] + lo] = R[a];
  };
  auto COMPUTE = [&](int b) {
    const unsigned short* hb = &st[b][0];
    short8 af[MI], bfv[NI];
#pragma unroll
    for (int mi = 0; mi < MI; mi++)
      af[mi] = *(const short8*)&hb[(wr * MI + mi) * 512 + lo];
#pragma unroll
    for (int ni = 0; ni < NI; ni++)
      bfv[ni] = *(const short8*)&hb[(NSUB_A + wc * NI + ni) * 512 + lo];
#pragma unroll
    for (int mi = 0; mi < MI; mi++)
#pragma unroll
      for (int ni = 0; ni < NI; ni++)
        acc[mi][ni] =
            __builtin_amdgcn_mfma_f32_16x16x32_bf16(af[mi], bfv[ni], acc[mi][ni], 0, 0, 0);
  };

  // prologue: tiles 0,1 into regs; tile 0 -> buf0
  LOADT(rA, 0);
  LOADT(rB2, 1);
  WRITET(rA, 0);
  __syncthreads();

  // unroll-2 steady state: tile k from buf0, k+1 from buf1; rA/rB2 rotate 2-deep.
  // Buffer b is overwritten only after the barrier that follows its last read.
  for (int k = 0; k < NK; k += 2) {
    if (k + 2 < NK) LOADT(rA, k + 2);   // issue early — flies during COMPUTE+write
    COMPUTE(0);                          // tile k
    WRITET(rB2, 1);                      // tile k+1 -> buf1 (vmcnt dep auto)
    __syncthreads();
    if (k + 3 < NK) LOADT(rB2, k + 3);
    COMPUTE(1);                          // tile k+1
    if (k + 2 < NK) WRITET(rA, 0);       // tile k+2 -> buf0
    __syncthreads();
  }

  if constexpr (MODE == 0) {
#pragma unroll
    for (int mi = 0; mi < MI; mi++) {
      int row = bm * MTILE + mi * 16 + quad * 4;
#pragma unroll
      for (int ni = 0; ni < NI; ni++) {
        int col = bn * 128 + wave * 32 + ni * 16 + l16;
#pragma unroll
        for (int rr = 0; rr < 4; rr++)
          outC[(size_t)(row + rr) * NEMB + col] = acc[mi][ni][rr] * INV_BETA;
      }
    }
  } else {
    // count epilogue: lane holds rows (wr*64+mi*16+quad*4+rr), cols (wc*64+ni*16+l16)
#pragma unroll
    for (int mi = 0; mi < MI; mi++) {
#pragma unroll
      for (int rr = 0; rr < 4; rr++) {
        int rloc = wr * 64 + mi * 16 + quad * 4 + rr;
        float s = saSh[rloc];
        int c = 0;
#pragma unroll
        for (int ni = 0; ni < NI; ni++) c += (acc[mi][ni][rr] > s) ? 1 : 0;
        c += __shfl_xor(c, 1, 64);
        c += __shfl_xor(c, 2, 64);
        c += __shfl_xor(c, 4, 64);
        c += __shfl_xor(c, 8, 64);
        if (l16 == 0) atomicAdd(&cntSh[rloc], c);
      }
    }
    __syncthreads();
    if (t < nvalid) atomicAdd(&cntOut[outRowSh[t]], cntSh[t]);
  }
}

// survivor compaction: rows with partial count < 6 need the remaining columns
__global__ __launch_bounds__(256) void compact_kernel(const int* __restrict__ cnt,
                                                      int* __restrict__ surv,
                                                      int* __restrict__ nsurv) {
  __shared__ int ctr;
  if (threadIdx.x == 0) ctr = 0;
  __syncthreads();
  for (int i = threadIdx.x; i < NR2; i += 256) {
    if (cnt[i] < 6) {
      int p = atomicAdd(&ctr, 1);
      surv[p] = i;
    }
  }
  __syncthreads();
  if (threadIdx.x == 0) nsurv[0] = ctr;
}

// single-pass: per-thread top6(v,i) + two-pass in-register softmax stats,
// then LDS tree merge. 1024 threads/block (16 elems/thread via 4x float4).
__global__ __launch_bounds__(1024) void rowstats_kernel(
    const float* __restrict__ logits, float* __restrict__ topv,
    int* __restrict__ topi, float* __restrict__ lse) {
  int m = blockIdx.x, t = threadIdx.x;
  const float4* row4 = (const float4*)(logits + (size_t)m * NEMB);
  float v6[6]; int i6[6];
#pragma unroll
  for (int j = 0; j < 6; j++) { v6[j] = NEG_INF; i6[j] = 0x7fffffff; }
  float vals[16];
#pragma unroll
  for (int j = 0; j < 4; j++) {
    float4 f = row4[t + j * 1024];
    vals[j * 4 + 0] = f.x; vals[j * 4 + 1] = f.y;
    vals[j * 4 + 2] = f.z; vals[j * 4 + 3] = f.w;
  }
  float mx = vals[0];
#pragma unroll
  for (int r = 1; r < 16; r++) mx = fmaxf(mx, vals[r]);
  float sme = 0.f;
#pragma unroll
  for (int r = 0; r < 16; r++) sme += expf(vals[r] - mx);
#pragma unroll
  for (int j = 0; j < 4; j++) {
    int base = (t + j * 1024) * 4;
#pragma unroll
    for (int b = 0; b < 4; b++) ins6i(vals[j * 4 + b], base + b, v6, i6);
  }
  __shared__ float sv[1024 * 6]; __shared__ int si[1024 * 6];
  __shared__ float smx[1024], ssm[1024];
#pragma unroll
  for (int j = 0; j < 6; j++) { sv[t * 6 + j] = v6[j]; si[t * 6 + j] = i6[j]; }
  smx[t] = mx; ssm[t] = sme;
  __syncthreads();
  for (int s = 512; s > 0; s >>= 1) {
    if (t < s) {
      float mo = smx[t + s], lo2 = ssm[t + s];
      float mn = fmaxf(smx[t], mo);
      ssm[t] = ssm[t] * expf(smx[t] - mn) + lo2 * expf(mo - mn);
      smx[t] = mn;
#pragma unroll
      for (int j = 0; j < 6; j++) ins6i(sv[(t + s) * 6 + j], si[(t + s) * 6 + j], v6, i6);
#pragma unroll
      for (int j = 0; j < 6; j++) { sv[t * 6 + j] = v6[j]; si[t * 6 + j] = i6[j]; }
    }
    __syncthreads();
  }
  if (t == 0) {
    lse[m] = smx[0] + logf(ssm[0]);
#pragma unroll
    for (int j = 0; j < 6; j++) { topv[m * 6 + j] = v6[j]; topi[m * 6 + j] = i6[j]; }
  }
}

// exact fp32 dot: sa[r] = em[topi[r]] . em[anchor(m=r/6)]; also zeroes cnt[r]
__global__ __launch_bounds__(256) void sa_kernel(const float* __restrict__ em,
                                                 const int* __restrict__ topi,
                                                 float* __restrict__ sa,
                                                 int* __restrict__ cnt) {
  int gid = blockIdx.x * 256 + threadIdx.x;
  int w = gid >> 6, lane = gid & 63;
  if (w >= NR2) return;
  if (lane == 1) cnt[w] = 0;
  int m = w / 6;
  int i = topi[w], a = topi[m * 6];
  const float* ei = em + (size_t)i * DIMK;
  const float* ea = em + (size_t)a * DIMK;
  float s = 0.f;
  for (int d = lane; d < DIMK; d += 64) s += ei[d] * ea[d];
#pragma unroll
  for (int off = 32; off > 0; off >>= 1) s += __shfl_down(s, off, 64);
  if (lane == 0) sa[w] = s;
}

// recip[r] == (count of sims values strictly greater than sa[r]) < 6
__global__ __launch_bounds__(256) void final_kernel(
    const float* __restrict__ logits, const float* __restrict__ topv,
    const int* __restrict__ topi, const float* __restrict__ lse_arr,
    const int* __restrict__ cnt, const int* __restrict__ targets,
    float* __restrict__ out) {
  int m = threadIdx.x;
  float lse = lse_arr[m];
  int tgt = targets[m];
  float tl = logits[(size_t)m * NEMB + tgt];
  float beta = 0.f, Ps = 0.f, nbp = 0.f;
  bool tin = false;
#pragma unroll
  for (int k = 0; k < 6; k++) {
    int idx = topi[m * 6 + k]; float v = topv[m * 6 + k];
    float p = expf(v - lse);
    if (idx == tgt) { tin = true; beta += (lse - v); Ps += p; }
    else if (cnt[m * 6 + k] < 6) { beta += 0.5f * (lse - v); Ps += p; nbp += p; }
  }
  if (!tin) { beta += (lse - tl); Ps += expf(tl - lse); }
  float alpha = 9.2103404f * (1.f - Ps) + 0.6931472f * nbp;
  __shared__ float sA[256], sB2[256];
  sA[m] = alpha; sB2[m] = beta;
  __syncthreads();
  for (int s = 128; s > 0; s >>= 1) {
    if (m < s) { sA[m] += sA[m + s]; sB2[m] += sB2[m + s]; }
    __syncthreads();
  }
  if (m == 0) { out[0] = 0.05f * sA[0] / 256.f; out[1] = sB2[0] / 256.f; }
}

extern "C" void kernel_launch(void* const* d_in, const int* in_sizes, int n_in,
                              void* d_out, int out_size, void* d_ws, size_t ws_size,
                              hipStream_t stream) {
  const float* x = (const float*)d_in[0];
  const float* em = (const float*)d_in[1];
  const int* targets = (const int*)d_in[2];
  char* ws = (char*)d_ws;
  unsigned short* em_bf = (unsigned short*)ws;                 // 67108864 B
  unsigned short* x_bf  = (unsigned short*)(ws + 67108864);    // 1048576 B
  float* logits = (float*)(ws + 68157440);                     // 16777216 B
  int*   cnt    = (int*)  (ws + 84934656);                     // 6144 B
  int*   surv   = (int*)  (ws + 84940800);                     // 6144 B
  int*   nsurv  = (int*)  (ws + 84946944);                     // 64 B
  float* topv   = (float*)(ws + 89653248);                     // 6144 B
  int*   topi   = (int*)  (ws + 89659392);                     // 6144 B
  float* lse    = (float*)(ws + 89665536);                     // 1024 B
  float* sa     = (float*)(ws + 89666560);                     // 6144 B

  cvt_kernel<<<dim3(32768), dim3(256), 0, stream>>>(em, em_bf, NEMB * DIMK / 4);
  cvt_kernel<<<dim3(512), dim3(256), 0, stream>>>(x, x_bf, NB * DIMK / 4);
  gemm_rs<0><<<dim3(128, 4), dim3(256), 0, stream>>>(
      x_bf, em_bf, (const int*)nullptr, logits, (const float*)nullptr, (int*)nullptr,
      (const int*)nullptr, (const int*)nullptr);
  rowstats_kernel<<<dim3(256), dim3(1024), 0, stream>>>(logits, topv, topi, lse);
  sa_kernel<<<dim3(384), dim3(256), 0, stream>>>(em, topi, sa, cnt);
  gemm_rs<1><<<dim3(16, 12), dim3(256), 0, stream>>>(
      em_bf, em_bf, topi, (float*)nullptr, sa, cnt, (const int*)nullptr,
      (const int*)nullptr);
  compact_kernel<<<dim3(1), dim3(256), 0, stream>>>(cnt, surv, nsurv);
  gemm_rs<2><<<dim3(112, 12), dim3(256), 0, stream>>>(
      em_bf, em_bf, topi, (float*)nullptr, sa, cnt, surv, nsurv);
  final_kernel<<<dim3(1), dim3(256), 0, stream>>>(logits, topv, topi, lse, cnt, targets,
                                                  (float*)d_out);
}